// Round 3
// baseline (120.720 us; speedup 1.0000x reference)
//
#include <hip/hip_runtime.h>
#include <math.h>

// NG=4, N=6, NFG=8, NFR=256, NACT=5, B=32768
// Augmented factorization: with f~ = [feat, 1] (9-vec),
//   sim[g,n,m] = f~_n^T Mt_g f~_m,  Mt_g = ([Wt_g | bt_g]^T [Wp_g | bp_g]) / 16   (9x9)
// Each block computes all 4 Mt_g redundantly (324 dot-256 tasks over 256 threads),
// then 64 elements x 4 g-lanes per element (block=256), single kernel, one barrier.

__launch_bounds__(256, 2)
__global__ void gcn_fused(const float* __restrict__ bfeat, const float* __restrict__ pos,
                          const float* __restrict__ W_ext, const float* __restrict__ b_ext,
                          const float* __restrict__ Wt, const float* __restrict__ bt,
                          const float* __restrict__ Wp, const float* __restrict__ bp,
                          const float* __restrict__ W_gcn, const float* __restrict__ W_act,
                          const float* __restrict__ b_act, float* __restrict__ out, int B) {
  __shared__ float sWext[64];
  __shared__ float sbext[8];
  __shared__ __align__(8) float sM[4 * 92];  // Mt: g-stride 92, row f1 stride 10 (even => float2 reads)
  __shared__ float sWgcn[4 * 65];            // pre-scaled by 0.25 (mean over NG folded in)
  __shared__ float sWact[40];
  __shared__ float sbact[5];

  const int tid = threadIdx.x;

  // ---------- Phase A: stage small weights + compute Mt (fused precompute) ----------
  if (tid < 64) sWext[tid] = W_ext[tid];
  if (tid < 8) sbext[tid] = b_ext[tid];
  sWgcn[(tid >> 6) * 65 + (tid & 63)] = 0.25f * W_gcn[tid];
  if (tid < 40) sWact[tid] = W_act[tid];
  if (tid < 5) sbact[tid] = b_act[tid];

  {
    // task tau -> (g, f1, f2); column f1 of [Wt|bt] dot column f2 of [Wp|bp], 256 long
    int tau = tid;
#pragma unroll 1
    for (int pass = 0; pass < 2; ++pass) {
      if (pass == 0 || tid < 68) {
        const int g1 = tau / 81, rem = tau % 81, f1 = rem / 9, f2 = rem % 9;
        const float* cA = (f1 < 8) ? (Wt + g1 * 2048 + f1) : (bt + g1 * 256);
        const int sA = (f1 < 8) ? 8 : 1;
        const float* cB = (f2 < 8) ? (Wp + g1 * 2048 + f2) : (bp + g1 * 256);
        const int sB = (f2 < 8) ? 8 : 1;
        const int sA2 = sA + sA, sA3 = sA2 + sA, sA4 = sA2 + sA2;
        const int sB2 = sB + sB, sB3 = sB2 + sB, sB4 = sB2 + sB2;
        float a0 = 0.0f, a1 = 0.0f, a2 = 0.0f, a3 = 0.0f;
#pragma unroll 4
        for (int r = 0; r < 64; ++r) {
          a0 = fmaf(cA[0], cB[0], a0);
          a1 = fmaf(cA[sA], cB[sB], a1);
          a2 = fmaf(cA[sA2], cB[sB2], a2);
          a3 = fmaf(cA[sA3], cB[sB3], a3);
          cA += sA4; cB += sB4;
        }
        sM[g1 * 92 + f1 * 10 + f2] = 0.0625f * ((a0 + a1) + (a2 + a3));
      }
      tau = 256 + tid;  // leftover tasks 256..323 on threads 0..67
    }
  }
  __syncthreads();

  // ---------- Phase B: per-element work: 4 lanes (one per g) per element ----------
  const int e = blockIdx.x * 64 + (tid >> 2);
  const int g = tid & 3;
  if (e >= B) return;

  float px[6], py[6];
  {
    const float4* p4 = (const float4*)(pos + (size_t)e * 12);
    float4 p0 = p4[0], p1 = p4[1], p2 = p4[2];
    px[0] = p0.x; py[0] = p0.y; px[1] = p0.z; py[1] = p0.w;
    px[2] = p1.x; py[2] = p1.y; px[3] = p1.z; py[3] = p1.w;
    px[4] = p2.x; py[4] = p2.y; px[5] = p2.z; py[5] = p2.w;
  }
  float bfr[6][8];
  {
    const float4* f4 = (const float4*)(bfeat + (size_t)e * 48);
#pragma unroll
    for (int i = 0; i < 12; ++i) {
      float4 v = f4[i];
      const int n = i >> 1, base = (i & 1) * 4;
      bfr[n][base + 0] = v.x; bfr[n][base + 1] = v.y;
      bfr[n][base + 2] = v.z; bfr[n][base + 3] = v.w;
    }
  }

  // ---- position mask: EXACT numpy fp32 sequence (do not touch) ----
  float rr[6];
#pragma unroll
  for (int n = 0; n < 6; ++n)
    rr[n] = __fadd_rn(__fmul_rn(px[n], px[n]), __fmul_rn(py[n], py[n]));
  unsigned long long mask = 0ull;
#pragma unroll
  for (int n = 0; n < 6; ++n) {
#pragma unroll
    for (int m = 0; m < 6; ++m) {
      float dot = __fadd_rn(__fmul_rn(px[n], px[m]), __fmul_rn(py[n], py[m]));
      float d2 = __fadd_rn(__fsub_rn(rr[n], __fmul_rn(2.0f, dot)), rr[m]);
      float dist = sqrtf(d2);  // NaN on diag -> false (matches np)
      if (dist > 4.0f) mask |= (1ull << (n * 6 + m));
    }
  }

  // ---- feature extension, split across the 4 g-lanes (2 output features each) ----
  // lane g computes o = 2g, 2g+1; then all-gather via wave shuffles (uniform src per o)
  float myo[6][2];
#pragma unroll
  for (int k = 0; k < 2; ++k) {
    const int o = 2 * g + k;
    const float bo = sbext[o];
#pragma unroll
    for (int n = 0; n < 6; ++n) {
      float s = bo;
#pragma unroll
      for (int f = 0; f < 8; ++f) s = fmaf(bfr[n][f], sWext[o * 8 + f], s);
      myo[n][k] = fmaxf(s, 0.0f);
    }
  }
  const int qbase = (tid & 63) & ~3;  // quad base lane within wave
  float feat[6][8];
#pragma unroll
  for (int n = 0; n < 6; ++n) {
#pragma unroll
    for (int o = 0; o < 8; ++o) {
      feat[n][o] = __shfl(myo[n][o & 1], qbase + (o >> 1), 64);
    }
  }
  // bfr is dead here (reloaded later for the residual) -> lower register peak

  // ---- th[n][j] = f~_n^T Mt_g  (9 wide; row 8 of Mt is the bias row) ----
  const float* Mg = sM + g * 92;
  float th[6][9];
  {
    const float2 c0 = *(const float2*)(Mg + 80);
    const float2 c1 = *(const float2*)(Mg + 82);
    const float2 c2 = *(const float2*)(Mg + 84);
    const float2 c3 = *(const float2*)(Mg + 86);
    const float r8 = Mg[88];
#pragma unroll
    for (int n = 0; n < 6; ++n) {
      th[n][0] = c0.x; th[n][1] = c0.y; th[n][2] = c1.x; th[n][3] = c1.y;
      th[n][4] = c2.x; th[n][5] = c2.y; th[n][6] = c3.x; th[n][7] = c3.y;
      th[n][8] = r8;
    }
  }
#pragma unroll
  for (int f = 0; f < 8; ++f) {
    const float2 a0 = *(const float2*)(Mg + f * 10 + 0);
    const float2 a1 = *(const float2*)(Mg + f * 10 + 2);
    const float2 a2 = *(const float2*)(Mg + f * 10 + 4);
    const float2 a3 = *(const float2*)(Mg + f * 10 + 6);
    const float a8 = Mg[f * 10 + 8];
#pragma unroll
    for (int n = 0; n < 6; ++n) {
      const float fv = feat[n][f];
      th[n][0] = fmaf(fv, a0.x, th[n][0]); th[n][1] = fmaf(fv, a0.y, th[n][1]);
      th[n][2] = fmaf(fv, a1.x, th[n][2]); th[n][3] = fmaf(fv, a1.y, th[n][3]);
      th[n][4] = fmaf(fv, a2.x, th[n][4]); th[n][5] = fmaf(fv, a2.y, th[n][5]);
      th[n][6] = fmaf(fv, a3.x, th[n][6]); th[n][7] = fmaf(fv, a3.y, th[n][7]);
      th[n][8] = fmaf(fv, a8,   th[n][8]);
    }
  }

  // ---- sim rows + softmax -> P (th dies after this) ----
  float P[6][6];
#pragma unroll
  for (int n = 0; n < 6; ++n) {
    float simr[6];
    float rmax = -INFINITY;
#pragma unroll
    for (int m = 0; m < 6; ++m) {
      float s = th[n][8];  // * f~[m][8] == 1
#pragma unroll
      for (int j = 0; j < 8; ++j) s = fmaf(th[n][j], feat[m][j], s);
      const bool msk = (mask >> (n * 6 + m)) & 1ull;
      simr[m] = msk ? -INFINITY : s;
      rmax = fmaxf(rmax, simr[m]);
    }
    float e6[6], esum = 0.0f;
#pragma unroll
    for (int m = 0; m < 6; ++m) {
      float ev = __expf(simr[m] - rmax);
      e6[m] = ev; esum += ev;
    }
    const float inv = 1.0f / esum;  // diag always unmasked
#pragma unroll
    for (int m = 0; m < 6; ++m) P[n][m] = e6[m] * inv;
  }

  // ---- agg = P @ feat (feat dies after) ----
  float agg[6][8];
#pragma unroll
  for (int n = 0; n < 6; ++n)
#pragma unroll
    for (int f = 0; f < 8; ++f) agg[n][f] = 0.0f;
#pragma unroll
  for (int m = 0; m < 6; ++m)
#pragma unroll
    for (int f = 0; f < 8; ++f) {
      const float fv = feat[m][f];
#pragma unroll
      for (int n = 0; n < 6; ++n) agg[n][f] = fmaf(P[n][m], fv, agg[n][f]);
    }

  // ---- con = relu(0.25*Wgcn_g @ agg) (o,f outer so each Wv LDS read serves 6 n) ----
  const float* Wg = sWgcn + g * 65;
  float con[6][8];
#pragma unroll
  for (int o = 0; o < 8; ++o) {
    float t6[6] = {0, 0, 0, 0, 0, 0};
#pragma unroll
    for (int f = 0; f < 8; ++f) {
      const float Wv = Wg[o * 8 + f];
#pragma unroll
      for (int n = 0; n < 6; ++n) t6[n] = fmaf(Wv, agg[n][f], t6[n]);
    }
#pragma unroll
    for (int n = 0; n < 6; ++n) con[n][o] = fmaxf(t6[n], 0.0f);
  }

  // ---- butterfly-sum across the 4 g-lanes ----
#pragma unroll
  for (int n = 0; n < 6; ++n)
#pragma unroll
    for (int f = 0; f < 8; ++f) {
      float v = con[n][f];
      v += __shfl_xor(v, 1);
      v += __shfl_xor(v, 2);
      con[n][f] = v;
    }

  // ---- residual (reload bfeat rows, L1-hot) + max-pool + activity head ----
  float pooled[8];
  {
    const float4* f4 = (const float4*)(bfeat + (size_t)e * 48);
#pragma unroll
    for (int f = 0; f < 8; ++f) pooled[f] = -INFINITY;
#pragma unroll
    for (int n = 0; n < 6; ++n) {
      float4 v0 = f4[n * 2], v1 = f4[n * 2 + 1];
      float row[8] = {v0.x, v0.y, v0.z, v0.w, v1.x, v1.y, v1.z, v1.w};
#pragma unroll
      for (int f = 0; f < 8; ++f) pooled[f] = fmaxf(pooled[f], con[n][f] + row[f]);
    }
  }
  float scg = sbact[g], sc4 = sbact[4];
#pragma unroll
  for (int f = 0; f < 8; ++f) {
    scg = fmaf(pooled[f], sWact[g * 8 + f], scg);
    sc4 = fmaf(pooled[f], sWact[4 * 8 + f], sc4);
  }
  const size_t ob = (size_t)e * 5;
  out[ob + g] = scg;
  if (g == 0) out[ob + 4] = sc4;
}

extern "C" void kernel_launch(void* const* d_in, const int* in_sizes, int n_in,
                              void* d_out, int out_size, void* d_ws, size_t ws_size,
                              hipStream_t stream) {
  const float* bfeat   = (const float*)d_in[0];
  const float* pos     = (const float*)d_in[1];
  const float* W_ext   = (const float*)d_in[2];
  const float* b_ext   = (const float*)d_in[3];
  const float* W_theta = (const float*)d_in[4];
  const float* b_theta = (const float*)d_in[5];
  const float* W_phi   = (const float*)d_in[6];
  const float* b_phi   = (const float*)d_in[7];
  const float* W_gcn   = (const float*)d_in[8];
  const float* W_act   = (const float*)d_in[9];
  const float* b_act   = (const float*)d_in[10];
  float* out = (float*)d_out;
  (void)d_ws; (void)ws_size;

  const int B = in_sizes[0] / 48;  // [B,6,8]
  const int grid = (B + 63) / 64;
  hipLaunchKernelGGL(gcn_fused, dim3(grid), dim3(256), 0, stream,
                     bfeat, pos, W_ext, b_ext, W_theta, b_theta, W_phi, b_phi,
                     W_gcn, W_act, b_act, out, B);
}

// Round 6
// 91.381 us; speedup vs baseline: 1.3211x; 1.3211x over previous
//
#include <hip/hip_runtime.h>
#include <math.h>

// NG=4, N=6, NFG=8, NFR=256, NACT=5, B=32768
// sim factorization: sim[g,n,m] = (f_n^T M_g f_m + U_g.f_n + V_g.f_m + C_g)/16
// ws layout (floats), R2-proven format, UNSCALED:
//   M[g*64+f1*8+f2] @0, U[g*8+f] @256, V[g*8+f] @288, C[g] @320   (324 floats)

// grid=81, block=256: one wave per ws entry; lane-parallel dot-256 + butterfly.
__launch_bounds__(256)
__global__ void gcn_precompute(const float* __restrict__ Wt, const float* __restrict__ bt,
                               const float* __restrict__ Wp, const float* __restrict__ bp,
                               float* __restrict__ ws) {
  const int wave = threadIdx.x >> 6, lane = threadIdx.x & 63;
  const int tau = blockIdx.x * 4 + wave;  // 81*4 = 324 exactly
  const float *cA, *cB;
  int sA, sB;
  if (tau < 256) {            // M[g][f1][f2] = sum_r Wt[g,r,f1]*Wp[g,r,f2]
    const int g = tau >> 6, f1 = (tau >> 3) & 7, f2 = tau & 7;
    cA = Wt + g * 2048 + f1; sA = 8;
    cB = Wp + g * 2048 + f2; sB = 8;
  } else if (tau < 288) {     // U[g][f] = sum_r Wt[g,r,f]*bp[g,r]
    const int i = tau - 256, g = i >> 3, f = i & 7;
    cA = Wt + g * 2048 + f;  sA = 8;
    cB = bp + g * 256;       sB = 1;
  } else if (tau < 320) {     // V[g][f] = sum_r Wp[g,r,f]*bt[g,r]
    const int i = tau - 288, g = i >> 3, f = i & 7;
    cA = Wp + g * 2048 + f;  sA = 8;
    cB = bt + g * 256;       sB = 1;
  } else {                    // C[g] = sum_r bt[g,r]*bp[g,r]
    const int g = tau - 320;
    cA = bt + g * 256; sA = 1;
    cB = bp + g * 256; sB = 1;
  }
  float s = 0.0f;
#pragma unroll
  for (int i = 0; i < 4; ++i) {
    const int r = lane + 64 * i;
    s = fmaf(cA[r * sA], cB[r * sB], s);
  }
#pragma unroll
  for (int off = 1; off < 64; off <<= 1) s += __shfl_xor(s, off, 64);
  if (lane == 0) ws[tau] = s;
}

// ===== R2's gcn_main, VERBATIM (passed @ absmax 0.0078) =====
// block=256: 64 elements/block, 4 lanes (one per g) per element. grid = B/64.
__launch_bounds__(256, 2)
__global__ void gcn_main(const float* __restrict__ bfeat, const float* __restrict__ pos,
                         const float* __restrict__ W_ext, const float* __restrict__ b_ext,
                         const float* __restrict__ W_gcn, const float* __restrict__ W_act,
                         const float* __restrict__ b_act, const float* __restrict__ ws,
                         float* __restrict__ out, int B) {
  // stride-65/9 padding: per-quad the 4 g-addresses land in 4 different banks
  __shared__ float sWext[64];
  __shared__ float sbext[8];
  __shared__ float sM[4 * 65];
  __shared__ float sU[4 * 9];
  __shared__ float sV[4 * 9];
  __shared__ float sC[4];
  __shared__ float sWgcn[4 * 65];  // pre-scaled by 0.25 (mean over NG folded in)
  __shared__ float sWact[40];
  __shared__ float sbact[5];

  const int tid = threadIdx.x;
  if (tid < 64) sWext[tid] = W_ext[tid];
  if (tid < 8) sbext[tid] = b_ext[tid];
  sM[(tid >> 6) * 65 + (tid & 63)] = ws[tid];
  if (tid < 32) sU[(tid >> 3) * 9 + (tid & 7)] = ws[256 + tid];
  if (tid < 32) sV[(tid >> 3) * 9 + (tid & 7)] = ws[288 + tid];
  if (tid < 4) sC[tid] = ws[320 + tid];
  sWgcn[(tid >> 6) * 65 + (tid & 63)] = 0.25f * W_gcn[tid];
  if (tid < 40) sWact[tid] = W_act[tid];
  if (tid < 5) sbact[tid] = b_act[tid];
  __syncthreads();

  const int e = blockIdx.x * 64 + (tid >> 2);  // batch element
  const int g = tid & 3;                       // relation group
  if (e >= B) return;

  // ---- load positions [6][2] ----
  float px[6], py[6];
  {
    const float4* p4 = (const float4*)(pos + (size_t)e * 12);
    float4 p0 = p4[0], p1 = p4[1], p2 = p4[2];
    px[0] = p0.x; py[0] = p0.y; px[1] = p0.z; py[1] = p0.w;
    px[2] = p1.x; py[2] = p1.y; px[3] = p1.z; py[3] = p1.w;
    px[4] = p2.x; py[4] = p2.y; px[5] = p2.z; py[5] = p2.w;
  }

  // ---- load raw features [6][8] ----
  float bfr[6][8];
  {
    const float4* f4 = (const float4*)(bfeat + (size_t)e * 48);
#pragma unroll
    for (int i = 0; i < 12; ++i) {
      float4 v = f4[i];
      const int n = i >> 1, base = (i & 1) * 4;
      bfr[n][base + 0] = v.x; bfr[n][base + 1] = v.y;
      bfr[n][base + 2] = v.z; bfr[n][base + 3] = v.w;
    }
  }

  // ---- position mask: replicate numpy fp32 rounding EXACTLY (no fma contraction) ----
  float rr[6];
#pragma unroll
  for (int n = 0; n < 6; ++n)
    rr[n] = __fadd_rn(__fmul_rn(px[n], px[n]), __fmul_rn(py[n], py[n]));
  unsigned long long mask = 0ull;  // bit n*6+m set => masked (-inf)
#pragma unroll
  for (int n = 0; n < 6; ++n) {
#pragma unroll
    for (int m = 0; m < 6; ++m) {
      float dot = __fadd_rn(__fmul_rn(px[n], px[m]), __fmul_rn(py[n], py[m]));
      float d2 = __fadd_rn(__fsub_rn(rr[n], __fmul_rn(2.0f, dot)), rr[m]);
      float dist = sqrtf(d2);  // NaN on diag -> false (matches np)
      if (dist > 4.0f) mask |= (1ull << (n * 6 + m));
    }
  }

  // ---- feature extension, split across the 4 g-lanes (2 output features each) ----
  float myo[6][2];
#pragma unroll
  for (int k = 0; k < 2; ++k) {
    const int o = 2 * g + k;
    const float bo = sbext[o];
#pragma unroll
    for (int n = 0; n < 6; ++n) {
      float s = bo;
#pragma unroll
      for (int f = 0; f < 8; ++f) s = fmaf(bfr[n][f], sWext[o * 8 + f], s);
      myo[n][k] = fmaxf(s, 0.0f);
    }
  }
  const int qbase = (tid & 63) & ~3;  // quad base lane within wave
  float feat[6][8];
#pragma unroll
  for (int n = 0; n < 6; ++n) {
#pragma unroll
    for (int o = 0; o < 8; ++o) {
      feat[n][o] = __shfl(myo[n][o & 1], qbase + (o >> 1), 64);
    }
  }

  // ---- con init: 0.25*bfr so the 4-lane sum contributes the residual exactly once ----
  float con[6][8];
#pragma unroll
  for (int n = 0; n < 6; ++n)
#pragma unroll
    for (int f = 0; f < 8; ++f) con[n][f] = 0.25f * bfr[n][f];

  // ---- this lane's group g ----
  const float* M = sM + g * 65;
  const float* U = sU + g * 9;
  const float* V = sV + g * 9;
  const float* Wg = sWgcn + g * 65;
  const float Cg = sC[g];

  // z[m][f1] = sum_f2 M[f1][f2]*feat[m][f2]
  float z[6][8];
#pragma unroll
  for (int m = 0; m < 6; ++m)
#pragma unroll
    for (int f1 = 0; f1 < 8; ++f1) z[m][f1] = 0.0f;
#pragma unroll
  for (int f1 = 0; f1 < 8; ++f1) {
#pragma unroll
    for (int f2 = 0; f2 < 8; ++f2) {
      const float Mv = M[f1 * 8 + f2];
#pragma unroll
      for (int m = 0; m < 6; ++m) z[m][f1] = fmaf(Mv, feat[m][f2], z[m][f1]);
    }
  }

  float uv[6], vv[6];
#pragma unroll
  for (int n = 0; n < 6; ++n) {
    float su = 0.0f, sv = 0.0f;
#pragma unroll
    for (int f = 0; f < 8; ++f) {
      su = fmaf(U[f], feat[n][f], su);
      sv = fmaf(V[f], feat[n][f], sv);
    }
    uv[n] = su; vv[n] = sv;
  }

  // sim + softmax -> P[6][6]
  float P[6][6];
#pragma unroll
  for (int n = 0; n < 6; ++n) {
    float simr[6];
    float rmax = -INFINITY;
#pragma unroll
    for (int m = 0; m < 6; ++m) {
      float s = 0.0f;
#pragma unroll
      for (int f = 0; f < 8; ++f) s = fmaf(feat[n][f], z[m][f], s);
      s = (s + uv[n] + vv[m] + Cg) * 0.0625f;
      const bool msk = (mask >> (n * 6 + m)) & 1ull;
      simr[m] = msk ? -INFINITY : s;
      rmax = fmaxf(rmax, simr[m]);
    }
    float e6[6], esum = 0.0f;
#pragma unroll
    for (int m = 0; m < 6; ++m) {
      float ev = __expf(simr[m] - rmax);
      e6[m] = ev; esum += ev;
    }
    const float inv = 1.0f / esum;  // diag always unmasked
#pragma unroll
    for (int m = 0; m < 6; ++m) P[n][m] = e6[m] * inv;
  }

  // agg[n][f] = sum_m P[n][m]*feat[m][f]
  float agg[6][8];
#pragma unroll
  for (int n = 0; n < 6; ++n)
#pragma unroll
    for (int f = 0; f < 8; ++f) agg[n][f] = 0.0f;
#pragma unroll
  for (int m = 0; m < 6; ++m)
#pragma unroll
    for (int f = 0; f < 8; ++f) {
      const float fv = feat[m][f];
#pragma unroll
      for (int n = 0; n < 6; ++n) agg[n][f] = fmaf(P[n][m], fv, agg[n][f]);
    }

  // con += relu(0.25*Wgcn_g @ agg)
#pragma unroll
  for (int o = 0; o < 8; ++o) {
    float t6[6] = {0, 0, 0, 0, 0, 0};
#pragma unroll
    for (int f = 0; f < 8; ++f) {
      const float Wv = Wg[o * 8 + f];
#pragma unroll
      for (int n = 0; n < 6; ++n) t6[n] = fmaf(Wv, agg[n][f], t6[n]);
    }
#pragma unroll
    for (int n = 0; n < 6; ++n) con[n][o] += fmaxf(t6[n], 0.0f);
  }

  // ---- butterfly-sum across the 4 g-lanes ----
#pragma unroll
  for (int n = 0; n < 6; ++n)
#pragma unroll
    for (int f = 0; f < 8; ++f) {
      float v = con[n][f];
      v += __shfl_xor(v, 1);
      v += __shfl_xor(v, 2);
      con[n][f] = v;
    }

  // ---- epilogue ----
  float pooled[8];
#pragma unroll
  for (int f = 0; f < 8; ++f) {
    float mx = con[0][f];
#pragma unroll
    for (int n = 1; n < 6; ++n) mx = fmaxf(mx, con[n][f]);
    pooled[f] = mx;
  }
  float scg = sbact[g], sc4 = sbact[4];
#pragma unroll
  for (int f = 0; f < 8; ++f) {
    scg = fmaf(pooled[f], sWact[g * 8 + f], scg);
    sc4 = fmaf(pooled[f], sWact[4 * 8 + f], sc4);
  }
  const size_t ob = (size_t)e * 5;
  out[ob + g] = scg;
  if (g == 0) out[ob + 4] = sc4;
}

extern "C" void kernel_launch(void* const* d_in, const int* in_sizes, int n_in,
                              void* d_out, int out_size, void* d_ws, size_t ws_size,
                              hipStream_t stream) {
  const float* bfeat   = (const float*)d_in[0];
  const float* pos     = (const float*)d_in[1];
  const float* W_ext   = (const float*)d_in[2];
  const float* b_ext   = (const float*)d_in[3];
  const float* W_theta = (const float*)d_in[4];
  const float* b_theta = (const float*)d_in[5];
  const float* W_phi   = (const float*)d_in[6];
  const float* b_phi   = (const float*)d_in[7];
  const float* W_gcn   = (const float*)d_in[8];
  const float* W_act   = (const float*)d_in[9];
  const float* b_act   = (const float*)d_in[10];
  float* out = (float*)d_out;
  float* ws  = (float*)d_ws;

  const int B = in_sizes[0] / 48;  // [B,6,8]

  hipLaunchKernelGGL(gcn_precompute, dim3(81), dim3(256), 0, stream,
                     W_theta, b_theta, W_phi, b_phi, ws);
  const int grid = (B + 63) / 64;
  hipLaunchKernelGGL(gcn_main, dim3(grid), dim3(256), 0, stream,
                     bfeat, pos, W_ext, b_ext, W_gcn, W_act, b_act, ws, out, B);
}